// Round 1
// baseline (302.741 us; speedup 1.0000x reference)
//
#include <hip/hip_runtime.h>
#include <math.h>

#define B_   8
#define C_   512
#define CQ   64
#define N_   4096
#define EPSF 1e-6f

// ---------------------------------------------------------------------------
// K1: per (b, 64-position chunk):
//   QK[128 m][64 n] = [Wq;Wk] @ x  (+bias), L2-normalize columns,
//   write Qn, Kn to global, atomicAdd Ksum[b][m], accumulate xsum[b][j].
// ---------------------------------------------------------------------------
__global__ __launch_bounds__(256) void k1_qk(
        const float* __restrict__ x,
        const float* __restrict__ Wq, const float* __restrict__ bq,
        const float* __restrict__ Wk, const float* __restrict__ bk,
        float* __restrict__ Qn, float* __restrict__ Kn,
        float* __restrict__ Ksum, float* __restrict__ xsum)
{
    const int b  = blockIdx.y;
    const int n0 = blockIdx.x * 64;
    const int tid = threadIdx.x;

    __shared__ float A_l[16][132];   // [k][m]   staged weights (transposed)
    __shared__ float Bx_l[16][68];   // [k][n]   staged x
    __shared__ float T[128][68];     // [m][n]   QK tile
    __shared__ float qinv[64], kinv[64];
    __shared__ float xs_l[512];

    const int tmh = tid >> 4;        // m-tile: m = tmh*8 .. +8
    const int tnh = tid & 15;        // n-tile: n = tnh*4 .. +4

    float acc[8][4];
#pragma unroll
    for (int i = 0; i < 8; i++)
#pragma unroll
        for (int j = 0; j < 4; j++) acc[i][j] = 0.f;

    const float* xb = x + (size_t)b * C_ * N_;

    for (int k0 = 0; k0 < C_; k0 += 16) {
        {   // stage A (weights, transposed into [k][m])
            int m_ld = tid >> 1;
            int kk0  = (tid & 1) * 8;
            const float* Wrow = (m_ld < 64) ? (Wq + (size_t)m_ld * C_)
                                            : (Wk + (size_t)(m_ld - 64) * C_);
#pragma unroll
            for (int i = 0; i < 8; i++)
                A_l[kk0 + i][m_ld] = Wrow[k0 + kk0 + i];
        }
        {   // stage B (x chunk)
            int kk = tid >> 4;
            int nn = (tid & 15) * 4;
            *(float4*)&Bx_l[kk][nn] =
                *(const float4*)(xb + (size_t)(k0 + kk) * N_ + n0 + nn);
        }
        __syncthreads();

        // xsum partial: column sums of staged x (each k staged exactly once)
        if (tid < 64) {
            int kk = tid >> 2, seg = tid & 3;
            float s = 0.f;
#pragma unroll
            for (int i = 0; i < 16; i++) s += Bx_l[kk][seg * 16 + i];
            s += __shfl_xor(s, 1);
            s += __shfl_xor(s, 2);
            if (seg == 0) xs_l[k0 + kk] = s;
        }

#pragma unroll
        for (int kk = 0; kk < 16; kk++) {
            float a[8], bb[4];
            *(float4*)(a)     = *(const float4*)&A_l[kk][tmh * 8];
            *(float4*)(a + 4) = *(const float4*)&A_l[kk][tmh * 8 + 4];
            *(float4*)(bb)    = *(const float4*)&Bx_l[kk][tnh * 4];
#pragma unroll
            for (int i = 0; i < 8; i++)
#pragma unroll
                for (int j = 0; j < 4; j++)
                    acc[i][j] += a[i] * bb[j];
        }
        __syncthreads();
    }

    // epilogue: add bias, park tile in LDS
    {
        int m0 = tmh * 8;
#pragma unroll
        for (int i = 0; i < 8; i++) {
            int m = m0 + i;
            float bias = (m < 64) ? bq[m] : bk[m - 64];
#pragma unroll
            for (int j = 0; j < 4; j++)
                T[m][tnh * 4 + j] = acc[i][j] + bias;
        }
    }
    __syncthreads();

    // column L2 norms (Q: m<64, K: m>=64)
    if (tid < 128) {
        int nn  = tid & 63;
        int isK = tid >> 6;
        float s = 0.f;
#pragma unroll
        for (int m = 0; m < 64; m++) {
            float v = T[isK * 64 + m][nn];
            s += v * v;
        }
        float inv = 1.f / sqrtf(s);
        if (isK) kinv[nn] = inv; else qinv[nn] = inv;
    }
    __syncthreads();

    // write Qn / Kn
    {
        float* Qb = Qn + (size_t)b * CQ * N_;
        float* Kb = Kn + (size_t)b * CQ * N_;
        for (int r = 0; r < 16; r++) {
            int idx = r * 256 + tid;       // 0..4095
            int m = idx >> 6, nn = idx & 63;
            Qb[(size_t)m * N_ + n0 + nn] = T[m][nn] * qinv[nn];
            Kb[(size_t)m * N_ + n0 + nn] = T[64 + m][nn] * kinv[nn];
        }
    }
    // Ksum partial
    if (tid < 64) {
        float s = 0.f;
        for (int nn = 0; nn < 64; nn++) s += T[64 + tid][nn] * kinv[nn];
        atomicAdd(&Ksum[b * CQ + tid], s);
    }
    // xsum partial
    atomicAdd(&xsum[b * C_ + tid], xs_l[tid]);
    atomicAdd(&xsum[b * C_ + 256 + tid], xs_l[256 + tid]);
}

// ---------------------------------------------------------------------------
// K2: KX[m][j] = sum_n Kn[m][n] * x[j][n]  -- split-K GEMM, partials to ws.
// grid (jt=8, ks=4, b=8), block 256. Each block: [64m x 64j] over 1024 n.
// ---------------------------------------------------------------------------
__global__ __launch_bounds__(256) void k2_kx(
        const float* __restrict__ x, const float* __restrict__ Kn,
        float* __restrict__ part)
{
    const int jt = blockIdx.x;
    const int ks = blockIdx.y;
    const int b  = blockIdx.z;
    const int j0 = jt * 64;
    const int nbase = ks * 1024;
    const int tid = threadIdx.x;

    __shared__ float Kl[32][68];   // [n][m]
    __shared__ float Xl[32][68];   // [n][j]

    const int tmh = tid >> 4;      // m = tmh*4
    const int tjh = tid & 15;      // j = tjh*4

    float acc[4][4] = {};
    const float* xb = x  + (size_t)b * C_ * N_;
    const float* Kb = Kn + (size_t)b * CQ * N_;

    for (int nc = 0; nc < 1024; nc += 32) {
        {
            int m = tid >> 2, nn0 = (tid & 3) * 8;
            const float* src = Kb + (size_t)m * N_ + nbase + nc + nn0;
#pragma unroll
            for (int i = 0; i < 8; i++) Kl[nn0 + i][m] = src[i];
        }
        {
            int jl = tid >> 2, nn0 = (tid & 3) * 8;
            const float* src = xb + (size_t)(j0 + jl) * N_ + nbase + nc + nn0;
#pragma unroll
            for (int i = 0; i < 8; i++) Xl[nn0 + i][jl] = src[i];
        }
        __syncthreads();
#pragma unroll
        for (int nn = 0; nn < 32; nn++) {
            float a[4], bb[4];
            *(float4*)a  = *(const float4*)&Kl[nn][tmh * 4];
            *(float4*)bb = *(const float4*)&Xl[nn][tjh * 4];
#pragma unroll
            for (int i = 0; i < 4; i++)
#pragma unroll
                for (int j = 0; j < 4; j++)
                    acc[i][j] += a[i] * bb[j];
        }
        __syncthreads();
    }
    float* p = part + ((size_t)(b * 4 + ks) * CQ) * C_;
#pragma unroll
    for (int i = 0; i < 4; i++) {
        float o[4] = {acc[i][0], acc[i][1], acc[i][2], acc[i][3]};
        *(float4*)&p[(size_t)(tmh * 4 + i) * C_ + j0 + tjh * 4] = *(float4*)o;
    }
}

// ---------------------------------------------------------------------------
// K3: reduce KX partials; matrix[m][c] = sum_j KX[m][j] Wv[c][j] + Ksum[m]bv[c]
//     value_sum[c] = sum_j Wv[c][j] xsum[j] + N*bv[c]
// grid (ct=8, b=8), block 256.
// ---------------------------------------------------------------------------
__global__ __launch_bounds__(256) void k3_matrix(
        const float* __restrict__ part,
        const float* __restrict__ Wv, const float* __restrict__ bv,
        const float* __restrict__ Ksum, const float* __restrict__ xsum,
        float* __restrict__ M, float* __restrict__ vs)
{
    const int ct = blockIdx.x;
    const int b  = blockIdx.y;
    const int c0 = ct * 64;
    const int tid = threadIdx.x;

    __shared__ float Al[32][68];   // [j][m]
    __shared__ float Bl[32][68];   // [j][c]
    __shared__ float xsl[32];
    __shared__ float Ksl[64], bvl[64];

    const int tmh = tid >> 4;      // m = tmh*4
    const int tch = tid & 15;      // c = tch*4

    float acc[4][4] = {};
    float vsacc[4]  = {};

    if (tid < 64) { Ksl[tid] = Ksum[b * CQ + tid]; bvl[tid] = bv[c0 + tid]; }

    for (int j0 = 0; j0 < C_; j0 += 32) {
        {   // reduce 4 split-K partials while staging
            int m = tid >> 2, jj0 = (tid & 3) * 8;
            const float* p0 = part + ((size_t)(b * 4) * CQ + m) * C_ + j0 + jj0;
            const size_t st = (size_t)CQ * C_;
#pragma unroll
            for (int i = 0; i < 8; i++)
                Al[jj0 + i][m] = p0[i] + p0[st + i] + p0[2 * st + i] + p0[3 * st + i];
        }
        {
            int cl = tid >> 2, jj0 = (tid & 3) * 8;
            const float* src = Wv + (size_t)(c0 + cl) * C_ + j0 + jj0;
#pragma unroll
            for (int i = 0; i < 8; i++) Bl[jj0 + i][cl] = src[i];
        }
        if (tid < 32) xsl[tid] = xsum[b * C_ + j0 + tid];
        __syncthreads();
#pragma unroll
        for (int jj = 0; jj < 32; jj++) {
            float a[4], bb[4];
            *(float4*)a  = *(const float4*)&Al[jj][tmh * 4];
            *(float4*)bb = *(const float4*)&Bl[jj][tch * 4];
            float xs = xsl[jj];
#pragma unroll
            for (int i = 0; i < 4; i++)
#pragma unroll
                for (int j = 0; j < 4; j++)
                    acc[i][j] += a[i] * bb[j];
#pragma unroll
            for (int j = 0; j < 4; j++) vsacc[j] += xs * bb[j];
        }
        __syncthreads();
    }

    float* Mb = M + (size_t)b * CQ * C_;
#pragma unroll
    for (int i = 0; i < 4; i++) {
        int m = tmh * 4 + i;
        float ks = Ksl[m];
        float o[4];
#pragma unroll
        for (int j = 0; j < 4; j++) o[j] = acc[i][j] + ks * bvl[tch * 4 + j];
        *(float4*)&Mb[(size_t)m * C_ + c0 + tch * 4] = *(float4*)o;
    }
    if (tmh == 0) {
#pragma unroll
        for (int j = 0; j < 4; j++) {
            int c = tch * 4 + j;
            vs[b * C_ + c0 + c] = vsacc[j] + (float)N_ * bvl[c];
        }
    }
}

// ---------------------------------------------------------------------------
// K4: ts[n] = 1/(N + Qn[:,n].(Ksum+eps));
//     out[c][n] = gamma * ts[n] * (vs[c] + sum_m Qn[m][n] M[m][c])
// grid (nt=64, b=8), block 256.
// ---------------------------------------------------------------------------
__global__ __launch_bounds__(256) void k4_out(
        const float* __restrict__ Qn,
        const float* __restrict__ M, const float* __restrict__ vs,
        const float* __restrict__ Ksum, const float* __restrict__ gamma,
        float* __restrict__ out)
{
    const int nt = blockIdx.x;
    const int b  = blockIdx.y;
    const int n0 = nt * 64;
    const int tid = threadIdx.x;

    __shared__ float Ql[64][68];   // [m][n]
    __shared__ float Ml[64][68];   // [m][c]
    __shared__ float Ksl[64], tsl[64], vsl[64];
    __shared__ float tspart[4][64];

    {   // stage Qn tile
        int m = tid >> 2, nn0 = (tid & 3) * 16;
        const float* src = Qn + ((size_t)b * CQ + m) * N_ + n0 + nn0;
#pragma unroll
        for (int i = 0; i < 16; i += 4)
            *(float4*)&Ql[m][nn0 + i] = *(const float4*)(src + i);
    }
    if (tid < 64) Ksl[tid] = Ksum[b * CQ + tid];
    __syncthreads();

    {   // taylor denominator
        int nn = tid & 63, seg = tid >> 6;
        float s = 0.f;
#pragma unroll
        for (int i = 0; i < 16; i++) {
            int m = seg * 16 + i;
            s += Ql[m][nn] * (Ksl[m] + EPSF);
        }
        tspart[seg][nn] = s;
    }
    __syncthreads();
    if (tid < 64) {
        float s = tspart[0][tid] + tspart[1][tid] + tspart[2][tid] + tspart[3][tid];
        tsl[tid] = 1.f / ((float)N_ + s);
    }
    __syncthreads();

    const float g = gamma[0];
    const int tch = tid >> 4;   // c = tch*4
    const int tnh = tid & 15;   // n = tnh*4
    float* ob = out + (size_t)b * C_ * N_;

    for (int c0 = 0; c0 < C_; c0 += 64) {
        {
            int m = tid >> 2, cc0 = (tid & 3) * 16;
            const float* src = M + ((size_t)b * CQ + m) * C_ + c0 + cc0;
#pragma unroll
            for (int i = 0; i < 16; i += 4)
                *(float4*)&Ml[m][cc0 + i] = *(const float4*)(src + i);
        }
        if (tid < 64) vsl[tid] = vs[b * C_ + c0 + tid];
        __syncthreads();

        float acc[4][4] = {};
#pragma unroll
        for (int m = 0; m < 64; m++) {
            float a[4], q[4];
            *(float4*)a = *(const float4*)&Ml[m][tch * 4];
            *(float4*)q = *(const float4*)&Ql[m][tnh * 4];
#pragma unroll
            for (int i = 0; i < 4; i++)
#pragma unroll
                for (int j = 0; j < 4; j++)
                    acc[i][j] += a[i] * q[j];
        }
#pragma unroll
        for (int i = 0; i < 4; i++) {
            int c = tch * 4 + i;
            float vsc = vsl[c];
            float o[4];
#pragma unroll
            for (int j = 0; j < 4; j++)
                o[j] = g * tsl[tnh * 4 + j] * (vsc + acc[i][j]);
            *(float4*)&ob[(size_t)(c0 + c) * N_ + n0 + tnh * 4] = *(float4*)o;
        }
        __syncthreads();
    }
}

// ---------------------------------------------------------------------------
extern "C" void kernel_launch(void* const* d_in, const int* in_sizes, int n_in,
                              void* d_out, int out_size, void* d_ws, size_t ws_size,
                              hipStream_t stream)
{
    (void)in_sizes; (void)n_in; (void)out_size; (void)ws_size;
    const float* x     = (const float*)d_in[0];
    const float* Wq    = (const float*)d_in[1];
    const float* bq    = (const float*)d_in[2];
    const float* Wk    = (const float*)d_in[3];
    const float* bk    = (const float*)d_in[4];
    const float* Wv    = (const float*)d_in[5];
    const float* bv    = (const float*)d_in[6];
    const float* gamma = (const float*)d_in[7];
    float* out = (float*)d_out;
    float* ws  = (float*)d_ws;

    float* Qn   = ws;                          // [8][64][4096]  2097152
    float* Kn   = Qn + (size_t)B_ * CQ * N_;   // [8][64][4096]  2097152
    float* Ksum = Kn + (size_t)B_ * CQ * N_;   // [8][64]        512
    float* xsum = Ksum + B_ * CQ;              // [8][512]       4096
    float* part = xsum + B_ * C_;              // [8][4][64][512] 1048576
    float* M    = part + (size_t)B_ * 4 * CQ * C_; // [8][64][512] 262144
    float* vs   = M + (size_t)B_ * CQ * C_;    // [8][512]       4096

    hipMemsetAsync(Ksum, 0, (B_ * CQ + B_ * C_) * sizeof(float), stream);

    k1_qk   <<<dim3(64, 8), 256, 0, stream>>>(x, Wq, bq, Wk, bk, Qn, Kn, Ksum, xsum);
    k2_kx   <<<dim3(8, 4, 8), 256, 0, stream>>>(x, Kn, part);
    k3_matrix<<<dim3(8, 8), 256, 0, stream>>>(part, Wv, bv, Ksum, xsum, M, vs);
    k4_out  <<<dim3(64, 8), 256, 0, stream>>>(Qn, M, vs, Ksum, gamma, out);
}

// Round 2
// 197.262 us; speedup vs baseline: 1.5347x; 1.5347x over previous
//
#include <hip/hip_runtime.h>
#include <math.h>

#define B_   8
#define C_   512
#define CQ   64
#define N_   4096
#define EPSF 1e-6f
#define LS   40    // LDS row stride (shorts) for 32-wide k chunks; 80 B = 5x16 B
#define LS2  72    // LDS row stride (shorts) for 64-wide k (K4); 144 B = 9x16 B

typedef short  shortx8 __attribute__((ext_vector_type(8)));
typedef short  shortx4 __attribute__((ext_vector_type(4)));
typedef float  floatx4 __attribute__((ext_vector_type(4)));

__device__ __forceinline__ short f2bf(float f) {
    unsigned u = __builtin_bit_cast(unsigned, f);
    u += 0x7FFFu + ((u >> 16) & 1u);
    return (short)(u >> 16);
}
__device__ __forceinline__ float bf2f(short h) {
    unsigned u = ((unsigned)(unsigned short)h) << 16;
    return __builtin_bit_cast(float, u);
}
__device__ __forceinline__ shortx8 ldf8(const short* p) {
    return *(const shortx8*)p;
}

// ---------------------------------------------------------------------------
// K1: QK = [Wq;Wk] @ x  (bf16 MFMA, fp32 x cast+transposed in-kernel),
//     +bias, column L2-norm; emits Qnt[b][n][m] bf16, Kn[b][m][n] bf16, Ksum.
// grid (nt=32, b=8), block 256 (4 waves: waveM=Q/K rows, waveN=n half).
// ---------------------------------------------------------------------------
__global__ __launch_bounds__(256, 1) void k1_qk(
    const float* __restrict__ x, const float* __restrict__ Wq, const float* __restrict__ bq,
    const float* __restrict__ Wk, const float* __restrict__ bk,
    short* __restrict__ Qnt, short* __restrict__ Kn, float* __restrict__ Ksum)
{
    const int b   = blockIdx.y;
    const int n0  = blockIdx.x * 128;
    const int tid = threadIdx.x;
    const int lane = tid & 63, wid = tid >> 6;
    const int waveM = wid >> 1, waveN = wid & 1;
    const int quad = lane >> 4, ln = lane & 15;

    __shared__ short A_l[2][128][LS];   // [k-buf][m][k]  Wqk bf16
    __shared__ short B_l[2][128][LS];   // [k-buf][n][k]  x^T bf16
    __shared__ float bias_l[128];

    if (tid < 128) bias_l[tid] = (tid < 64) ? bq[tid] : bk[tid - 64];

    const int mA  = tid >> 1, koA = (tid & 1) * 16;          // A staging map
    const float* Arow = (mA < 64) ? (Wq + (size_t)mA * C_) : (Wk + (size_t)(mA - 64) * C_);
    const int kB  = tid & 31, gB = tid >> 5, nbB = (tid >> 5) * 16;  // B staging map
    const float* xb = x + (size_t)b * C_ * N_;

    float4 aC[4], bC[4];
#pragma unroll
    for (int i = 0; i < 4; i++) aC[i] = *(const float4*)(Arow + koA + i * 4);
    {
        const float* xr = xb + (size_t)kB * N_ + n0 + nbB;
#pragma unroll
        for (int i = 0; i < 4; i++) bC[i] = *(const float4*)(xr + i * 4);
    }

    auto stage = [&](int buf, const float4* av, const float4* bv2) {
        const float* af = (const float*)av;
#pragma unroll
        for (int i = 0; i < 16; i++) A_l[buf][mA][koA + i] = f2bf(af[i]);
        const float* bf = (const float*)bv2;
#pragma unroll
        for (int i = 0; i < 16; i++) {
            int r = (i + 2 * gB) & 15;              // stagger rows across groups (banks)
            B_l[buf][nbB + r][kB] = f2bf(bf[r]);
        }
    };
    stage(0, aC, bC);
    __syncthreads();

    const floatx4 z4 = {0.f, 0.f, 0.f, 0.f};
    floatx4 acc[4][4];
#pragma unroll
    for (int mt = 0; mt < 4; mt++)
#pragma unroll
        for (int nt = 0; nt < 4; nt++) acc[mt][nt] = z4;

    int cur = 0;
    for (int it = 0; it < 16; ++it) {
        float4 aN[4], bN[4];
        if (it < 15) {
            const int k0 = (it + 1) * 32;
#pragma unroll
            for (int i = 0; i < 4; i++) aN[i] = *(const float4*)(Arow + k0 + koA + i * 4);
            const float* xr = xb + (size_t)(k0 + kB) * N_ + n0 + nbB;
#pragma unroll
            for (int i = 0; i < 4; i++) bN[i] = *(const float4*)(xr + i * 4);
        }
        shortx8 af4[4];
#pragma unroll
        for (int mt = 0; mt < 4; mt++)
            af4[mt] = ldf8(&A_l[cur][waveM * 64 + mt * 16 + ln][quad * 8]);
#pragma unroll
        for (int nt = 0; nt < 4; nt++) {
            shortx8 bf8 = ldf8(&B_l[cur][waveN * 64 + nt * 16 + ln][quad * 8]);
#pragma unroll
            for (int mt = 0; mt < 4; mt++)
                acc[mt][nt] = __builtin_amdgcn_mfma_f32_16x16x32_bf16(af4[mt], bf8, acc[mt][nt], 0, 0, 0);
        }
        if (it < 15) stage(cur ^ 1, aN, bN);
        __syncthreads();
        cur ^= 1;
    }

    // bias
#pragma unroll
    for (int mt = 0; mt < 4; mt++)
#pragma unroll
        for (int r = 0; r < 4; r++) {
            float bias = bias_l[waveM * 64 + mt * 16 + quad * 4 + r];
#pragma unroll
            for (int nt = 0; nt < 4; nt++) acc[mt][nt][r] += bias;
        }
    // column L2 normalize (wave's 64 rows are exactly Q or exactly K)
#pragma unroll
    for (int nt = 0; nt < 4; nt++) {
        float s = 0.f;
#pragma unroll
        for (int mt = 0; mt < 4; mt++)
#pragma unroll
            for (int r = 0; r < 4; r++) s += acc[mt][nt][r] * acc[mt][nt][r];
        s += __shfl_xor(s, 16);
        s += __shfl_xor(s, 32);
        float inv = rsqrtf(s);
#pragma unroll
        for (int mt = 0; mt < 4; mt++)
#pragma unroll
            for (int r = 0; r < 4; r++) acc[mt][nt][r] *= inv;
    }

    if (waveM == 0) {            // Qn^T [n][m]
        short* Qb = Qnt + (size_t)b * N_ * CQ;
#pragma unroll
        for (int nt = 0; nt < 4; nt++) {
            int n = n0 + waveN * 64 + nt * 16 + ln;
#pragma unroll
            for (int mt = 0; mt < 4; mt++) {
                shortx4 v;
#pragma unroll
                for (int r = 0; r < 4; r++) v[r] = f2bf(acc[mt][nt][r]);
                *(shortx4*)(Qb + (size_t)n * CQ + mt * 16 + quad * 4) = v;
            }
        }
    } else {                     // Kn [m][n] + Ksum
        short* Kb = Kn + (size_t)b * CQ * N_;
#pragma unroll
        for (int mt = 0; mt < 4; mt++)
#pragma unroll
            for (int r = 0; r < 4; r++) {
                int m = mt * 16 + quad * 4 + r;
                float s = 0.f;
#pragma unroll
                for (int nt = 0; nt < 4; nt++) {
                    int n = n0 + waveN * 64 + nt * 16 + ln;
                    float v = acc[mt][nt][r];
                    Kb[(size_t)m * N_ + n] = f2bf(v);
                    s += v;
                }
                s += __shfl_xor(s, 1); s += __shfl_xor(s, 2);
                s += __shfl_xor(s, 4); s += __shfl_xor(s, 8);
                if (ln == 0) atomicAdd(&Ksum[b * CQ + m], s);
            }
    }
}

// ---------------------------------------------------------------------------
// K2: KX[m][j] += sum_n Kn[m][n]*x[j][n]  (NT MFMA, split-K over n, fp32 atomics)
//     + xsum[j]. grid (jt=4, ks=8, b=8), block 256 (waves split j).
// ---------------------------------------------------------------------------
__global__ __launch_bounds__(256, 1) void k2_kx(
    const float* __restrict__ x, const short* __restrict__ Kn,
    float* __restrict__ KX, float* __restrict__ xsum)
{
    const int jt = blockIdx.x, ks = blockIdx.y, b = blockIdx.z;
    const int j0 = jt * 128, nb0 = ks * 512;
    const int tid = threadIdx.x;
    const int lane = tid & 63, wid = tid >> 6;
    const int quad = lane >> 4, ln = lane & 15;

    __shared__ short A_l[2][64][LS];    // Kn rows m
    __shared__ short B_l[2][128][LS];   // x rows j (cast bf16)

    const int mA = tid >> 2, qA = tid & 3;
    const int jB = tid >> 1, hB = tid & 1;
    const short* Kb = Kn + (size_t)b * CQ * N_;
    const float* xb = x + (size_t)b * C_ * N_;

    float xsacc = 0.f;

    shortx8 aC; float4 bC[4];
    aC = *(const shortx8*)(Kb + (size_t)mA * N_ + nb0 + qA * 8);
    {
        const float* xr = xb + (size_t)(j0 + jB) * N_ + nb0 + hB * 16;
#pragma unroll
        for (int i = 0; i < 4; i++) bC[i] = *(const float4*)(xr + i * 4);
    }
    auto stage = [&](int buf, shortx8 a, const float4* bv2) {
        *(shortx8*)&A_l[buf][mA][qA * 8] = a;
        const float* bf = (const float*)bv2;
        shortx8 t0, t1;
#pragma unroll
        for (int i = 0; i < 8; i++) {
            t0[i] = f2bf(bf[i]);     xsacc += bf[i];
            t1[i] = f2bf(bf[i + 8]); xsacc += bf[i + 8];
        }
        *(shortx8*)&B_l[buf][jB][hB * 16]     = t0;
        *(shortx8*)&B_l[buf][jB][hB * 16 + 8] = t1;
    };
    stage(0, aC, bC);
    __syncthreads();

    const floatx4 z4 = {0.f, 0.f, 0.f, 0.f};
    floatx4 acc[4][2];
#pragma unroll
    for (int mt = 0; mt < 4; mt++) { acc[mt][0] = z4; acc[mt][1] = z4; }

    int cur = 0;
    for (int it = 0; it < 16; ++it) {
        shortx8 aN; float4 bN[4];
        if (it < 15) {
            const int nn = nb0 + (it + 1) * 32;
            aN = *(const shortx8*)(Kb + (size_t)mA * N_ + nn + qA * 8);
            const float* xr = xb + (size_t)(j0 + jB) * N_ + nn + hB * 16;
#pragma unroll
            for (int i = 0; i < 4; i++) bN[i] = *(const float4*)(xr + i * 4);
        }
        shortx8 af4[4];
#pragma unroll
        for (int mt = 0; mt < 4; mt++)
            af4[mt] = ldf8(&A_l[cur][mt * 16 + ln][quad * 8]);
#pragma unroll
        for (int jt2 = 0; jt2 < 2; jt2++) {
            shortx8 bf8 = ldf8(&B_l[cur][wid * 32 + jt2 * 16 + ln][quad * 8]);
#pragma unroll
            for (int mt = 0; mt < 4; mt++)
                acc[mt][jt2] = __builtin_amdgcn_mfma_f32_16x16x32_bf16(af4[mt], bf8, acc[mt][jt2], 0, 0, 0);
        }
        if (it < 15) stage(cur ^ 1, aN, bN);
        __syncthreads();
        cur ^= 1;
    }

    xsacc += __shfl_xor(xsacc, 1);
    if (hB == 0) atomicAdd(&xsum[b * C_ + j0 + jB], xsacc);

    float* KXb = KX + (size_t)b * CQ * C_;
#pragma unroll
    for (int mt = 0; mt < 4; mt++)
#pragma unroll
        for (int jt2 = 0; jt2 < 2; jt2++)
#pragma unroll
            for (int r = 0; r < 4; r++) {
                int m = mt * 16 + quad * 4 + r;
                int j = j0 + wid * 32 + jt2 * 16 + ln;
                atomicAdd(&KXb[(size_t)m * C_ + j], acc[mt][jt2][r]);
            }
}

// ---------------------------------------------------------------------------
// K3: Mt[c][m] += sum_j KX[m][j]*Wv[c][j] (+ Ksum[m]*bv[c] on jh==0),
//     vs[c] += sum_j Wv[c][j]*xsum[j]. grid (ct=8, jh=4, b=8), block 256.
// ---------------------------------------------------------------------------
__global__ __launch_bounds__(256, 1) void k3_m(
    const float* __restrict__ KX, const float* __restrict__ Wv,
    const float* __restrict__ bv, const float* __restrict__ Ksum,
    const float* __restrict__ xsum,
    float* __restrict__ Mtf, float* __restrict__ vs)
{
    const int ct = blockIdx.x, jh = blockIdx.y, b = blockIdx.z;
    const int c0 = ct * 64, jb0 = jh * 128;
    const int tid = threadIdx.x;
    const int lane = tid & 63, wid = tid >> 6;
    const int quad = lane >> 4, ln = lane & 15;

    __shared__ short A_l[2][64][LS];   // KX rows m (bf16)
    __shared__ short B_l[2][64][LS];   // Wv rows c (bf16)
    __shared__ float xsl[128], Ks_l[64], vsp[4][64];

    if (tid < 128) xsl[tid] = xsum[(size_t)b * C_ + jb0 + tid];
    if (tid >= 128 && tid < 192) Ks_l[tid - 128] = Ksum[b * CQ + tid - 128];

    const int rA = tid >> 2, qA = tid & 3;   // shared staging map (64 rows x 32)
    const float* Asrc = KX + ((size_t)b * CQ + rA) * C_ + jb0 + qA * 8;
    const float* Bsrc = Wv + (size_t)(c0 + rA) * C_ + jb0 + qA * 8;

    float4 aC[2], bC[2];
    aC[0] = *(const float4*)(Asrc);     aC[1] = *(const float4*)(Asrc + 4);
    bC[0] = *(const float4*)(Bsrc);     bC[1] = *(const float4*)(Bsrc + 4);

    auto stage = [&](int buf, const float4* a, const float4* bb) {
        const float* af = (const float*)a;
        const float* bf = (const float*)bb;
        shortx8 ta, tb;
#pragma unroll
        for (int i = 0; i < 8; i++) { ta[i] = f2bf(af[i]); tb[i] = f2bf(bf[i]); }
        *(shortx8*)&A_l[buf][rA][qA * 8] = ta;
        *(shortx8*)&B_l[buf][rA][qA * 8] = tb;
    };
    stage(0, aC, bC);
    __syncthreads();

    const floatx4 z4 = {0.f, 0.f, 0.f, 0.f};
    floatx4 acc[4] = {z4, z4, z4, z4};
    float vsacc = 0.f;

    int cur = 0;
    for (int it = 0; it < 4; ++it) {
        float4 aN[2], bN[2];
        if (it < 3) {
            const float* A2 = Asrc + (it + 1) * 32;
            const float* B2 = Bsrc + (it + 1) * 32;
            aN[0] = *(const float4*)(A2); aN[1] = *(const float4*)(A2 + 4);
            bN[0] = *(const float4*)(B2); bN[1] = *(const float4*)(B2 + 4);
        }
        shortx8 af4[4];
#pragma unroll
        for (int mt = 0; mt < 4; mt++)
            af4[mt] = ldf8(&A_l[cur][mt * 16 + ln][quad * 8]);
        shortx8 bf8 = ldf8(&B_l[cur][wid * 16 + ln][quad * 8]);
#pragma unroll
        for (int mt = 0; mt < 4; mt++)
            acc[mt] = __builtin_amdgcn_mfma_f32_16x16x32_bf16(af4[mt], bf8, acc[mt], 0, 0, 0);
        // vs partial from staged Wv tile: c = lane, j-range per wave
#pragma unroll
        for (int jj = 0; jj < 8; jj++)
            vsacc += bf2f(B_l[cur][lane][wid * 8 + jj]) * xsl[it * 32 + wid * 8 + jj];
        if (it < 3) stage(cur ^ 1, aN, bN);
        __syncthreads();
        cur ^= 1;
    }

    vsp[wid][lane] = vsacc;
    __syncthreads();
    if (tid < 64)
        atomicAdd(&vs[(size_t)b * C_ + c0 + tid],
                  vsp[0][tid] + vsp[1][tid] + vsp[2][tid] + vsp[3][tid]);

    const int cl = wid * 16 + ln;
    const float bvc = bv[c0 + cl];
    float* Mb = Mtf + ((size_t)b * C_ + c0 + cl) * CQ;
#pragma unroll
    for (int mt = 0; mt < 4; mt++)
#pragma unroll
        for (int r = 0; r < 4; r++) {
            int m = mt * 16 + quad * 4 + r;
            float v = acc[mt][r];
            if (jh == 0) v += Ks_l[m] * bvc;
            atomicAdd(&Mb[m], v);
        }
}

// ---------------------------------------------------------------------------
// K4: ts[n] = 1/(N + Qn[:,n].(Ksum+eps));
//     out[c][n] = gamma*ts[n]*(vs[c]+N*bv[c] + sum_m Qn[m][n]*M[m][c])
// grid (nt=32, ct=4, b=8), block 256 (2x2 waves, 128c x 128n tile, k=64).
// ---------------------------------------------------------------------------
__global__ __launch_bounds__(256, 1) void k4_out(
    const short* __restrict__ Qnt, const float* __restrict__ Mtf,
    const float* __restrict__ vs, const float* __restrict__ bv,
    const float* __restrict__ Ksum, const float* __restrict__ gamma,
    float* __restrict__ out)
{
    const int nt = blockIdx.x, ct = blockIdx.y, b = blockIdx.z;
    const int n0 = nt * 128, c0 = ct * 128;
    const int tid = threadIdx.x;
    const int lane = tid & 63, wid = tid >> 6;
    const int waveC = wid >> 1, waveN = wid & 1;
    const int quad = lane >> 4, ln = lane & 15;

    __shared__ short A_l[128][LS2];   // Mt rows c (bf16), k=m 0..63
    __shared__ short B_l[128][LS2];   // Qnt rows n (bf16)
    __shared__ float tsl[128], vsl[128], Ks_l[64];

    {   // stage A from Mtf fp32
        int c = tid >> 1, h = tid & 1;
        const float* src = Mtf + ((size_t)b * C_ + c0 + c) * CQ + h * 32;
#pragma unroll
        for (int q = 0; q < 4; q++) {
            float4 v = *(const float4*)(src + q * 8);
            float4 w = *(const float4*)(src + q * 8 + 4);
            shortx8 t;
            t[0] = f2bf(v.x); t[1] = f2bf(v.y); t[2] = f2bf(v.z); t[3] = f2bf(v.w);
            t[4] = f2bf(w.x); t[5] = f2bf(w.y); t[6] = f2bf(w.z); t[7] = f2bf(w.w);
            *(shortx8*)&A_l[c][h * 32 + q * 8] = t;
        }
    }
    {   // stage B from Qnt bf16
        int n = tid >> 1, h = tid & 1;
        const short* src = Qnt + ((size_t)b * N_ + n0 + n) * CQ + h * 32;
#pragma unroll
        for (int q = 0; q < 4; q++)
            *(shortx8*)&B_l[n][h * 32 + q * 8] = *(const shortx8*)(src + q * 8);
    }
    if (tid < 64)  Ks_l[tid] = Ksum[b * CQ + tid];
    if (tid < 128) vsl[tid]  = vs[(size_t)b * C_ + c0 + tid] + (float)N_ * bv[c0 + tid];
    __syncthreads();

    if (tid < 128) {
        const short* row = B_l[tid];
        float s = 0.f;
#pragma unroll
        for (int m = 0; m < 64; m++) s += bf2f(row[m]) * (Ks_l[m] + EPSF);
        tsl[tid] = 1.f / ((float)N_ + s);
    }
    __syncthreads();

    const floatx4 z4 = {0.f, 0.f, 0.f, 0.f};
    floatx4 acc[4][4];
#pragma unroll
    for (int i = 0; i < 4; i++)
#pragma unroll
        for (int j = 0; j < 4; j++) acc[i][j] = z4;

#pragma unroll
    for (int kc = 0; kc < 2; kc++) {
        shortx8 af4[4];
#pragma unroll
        for (int ct2 = 0; ct2 < 4; ct2++)
            af4[ct2] = ldf8(&A_l[waveC * 64 + ct2 * 16 + ln][kc * 32 + quad * 8]);
#pragma unroll
        for (int nt2 = 0; nt2 < 4; nt2++) {
            shortx8 bf8 = ldf8(&B_l[waveN * 64 + nt2 * 16 + ln][kc * 32 + quad * 8]);
#pragma unroll
            for (int ct2 = 0; ct2 < 4; ct2++)
                acc[ct2][nt2] = __builtin_amdgcn_mfma_f32_16x16x32_bf16(af4[ct2], bf8, acc[ct2][nt2], 0, 0, 0);
        }
    }

    const float g = gamma[0];
    float* ob = out + (size_t)b * C_ * N_;
#pragma unroll
    for (int ct2 = 0; ct2 < 4; ct2++)
#pragma unroll
        for (int r = 0; r < 4; r++) {
            int cl = waveC * 64 + ct2 * 16 + quad * 4 + r;
            float vc = vsl[cl];
#pragma unroll
            for (int nt2 = 0; nt2 < 4; nt2++) {
                int nl = waveN * 64 + nt2 * 16 + ln;
                ob[(size_t)(c0 + cl) * N_ + n0 + nl] = g * tsl[nl] * (vc + acc[ct2][nt2][r]);
            }
        }
}

// ---------------------------------------------------------------------------
extern "C" void kernel_launch(void* const* d_in, const int* in_sizes, int n_in,
                              void* d_out, int out_size, void* d_ws, size_t ws_size,
                              hipStream_t stream)
{
    (void)in_sizes; (void)n_in; (void)out_size; (void)ws_size;
    const float* x     = (const float*)d_in[0];
    const float* Wq    = (const float*)d_in[1];
    const float* bq    = (const float*)d_in[2];
    const float* Wk    = (const float*)d_in[3];
    const float* bk    = (const float*)d_in[4];
    const float* Wv    = (const float*)d_in[5];
    const float* bv    = (const float*)d_in[6];
    const float* gamma = (const float*)d_in[7];
    float* out = (float*)d_out;

    char* w = (char*)d_ws;
    short* Qnt = (short*)w;                 w += (size_t)B_ * N_ * CQ * 2;   // 4 MB
    short* Kn  = (short*)w;                 w += (size_t)B_ * CQ * N_ * 2;   // 4 MB
    float* Ksum = (float*)w;                w += (size_t)B_ * CQ * 4;
    float* xsum = (float*)w;                w += (size_t)B_ * C_ * 4;
    float* KX   = (float*)w;                w += (size_t)B_ * CQ * C_ * 4;   // 1 MB
    float* Mtf  = (float*)w;                w += (size_t)B_ * C_ * CQ * 4;   // 1 MB
    float* vs   = (float*)w;                w += (size_t)B_ * C_ * 4;

    // zero the accumulated tensors (Ksum..vs are contiguous)
    size_t zbytes = (size_t)(B_ * CQ + B_ * C_ + B_ * CQ * C_ + B_ * C_ * CQ + B_ * C_) * 4;
    hipMemsetAsync(Ksum, 0, zbytes, stream);

    k1_qk <<<dim3(32, 8),    256, 0, stream>>>(x, Wq, bq, Wk, bk, Qnt, Kn, Ksum);
    k2_kx <<<dim3(4, 8, 8),  256, 0, stream>>>(x, Kn, KX, xsum);
    k3_m  <<<dim3(8, 4, 8),  256, 0, stream>>>(KX, Wv, bv, Ksum, xsum, Mtf, vs);
    k4_out<<<dim3(32, 4, 8), 256, 0, stream>>>(Qnt, Mtf, vs, bv, Ksum, gamma, out);
}

// Round 3
// 185.386 us; speedup vs baseline: 1.6330x; 1.0641x over previous
//
#include <hip/hip_runtime.h>
#include <math.h>

#define B_   8
#define C_   512
#define CQ   64
#define N_   4096
#define EPSF 1e-6f
#define LS   40    // LDS row stride (shorts) for 32-wide k chunks; 80 B = 5x16 B
#define LS2  72    // LDS row stride (shorts) for 64-wide k (K4); 144 B = 9x16 B

typedef short  shortx8 __attribute__((ext_vector_type(8)));
typedef short  shortx4 __attribute__((ext_vector_type(4)));
typedef short  shortx2 __attribute__((ext_vector_type(2)));
typedef float  floatx4 __attribute__((ext_vector_type(4)));

__device__ __forceinline__ short f2bf(float f) {
    unsigned u = __builtin_bit_cast(unsigned, f);
    u += 0x7FFFu + ((u >> 16) & 1u);
    return (short)(u >> 16);
}
__device__ __forceinline__ float bf2f(short h) {
    unsigned u = ((unsigned)(unsigned short)h) << 16;
    return __builtin_bit_cast(float, u);
}
__device__ __forceinline__ shortx8 ldf8(const short* p) {
    return *(const shortx8*)p;
}

// ---------------------------------------------------------------------------
// P: cast weights to bf16. Wqk[128][512] = [Wq;Wk], Wvb[512][512].
// ---------------------------------------------------------------------------
__global__ __launch_bounds__(256) void pcast(
    const float* __restrict__ Wq, const float* __restrict__ Wk,
    const float* __restrict__ Wv, short* __restrict__ Wqk, short* __restrict__ Wvb)
{
    int i = (blockIdx.x * 256 + threadIdx.x) * 4;
    float4 v; short* dst;
    if (i < 2 * CQ * C_) {
        const float* src = (i < CQ * C_) ? (Wq + i) : (Wk + i - CQ * C_);
        v = *(const float4*)src;
        dst = Wqk + i;
    } else {
        int j = i - 2 * CQ * C_;
        v = *(const float4*)(Wv + j);
        dst = Wvb + j;
    }
    const float* f = (const float*)&v;
    shortx4 o = { f2bf(f[0]), f2bf(f[1]), f2bf(f[2]), f2bf(f[3]) };
    *(shortx4*)dst = o;
}

// ---------------------------------------------------------------------------
// K1: QK = [Wq;Wk] @ x (bf16 MFMA), +bias, column L2-norm;
//     emits Qnt[b][n][m] bf16, Kn[b][m][n] bf16, Ksum (atomic).
// grid (nt=64, b=8) = 512 blocks, block 256 (waveM = Q/K half, waveN = n half).
// ---------------------------------------------------------------------------
__global__ __launch_bounds__(256, 2) void k1_qk(
    const float* __restrict__ x, const short* __restrict__ Wqk,
    const float* __restrict__ bq, const float* __restrict__ bk,
    short* __restrict__ Qnt, short* __restrict__ Kn, float* __restrict__ Ksum)
{
    const int b   = blockIdx.y;
    const int n0  = blockIdx.x * 64;
    const int tid = threadIdx.x;
    const int lane = tid & 63, wid = tid >> 6;
    const int waveM = wid >> 1, waveN = wid & 1;
    const int quad = lane >> 4, ln = lane & 15;

    __shared__ short A_l[2][128][LS];   // [buf][m][k] Wqk bf16
    __shared__ short B_l[2][64][LS];    // [buf][n][k] x^T bf16
    __shared__ float bias_l[128];

    if (tid < 128) bias_l[tid] = (tid < 64) ? bq[tid] : bk[tid - 64];

    const int mA = tid >> 1, koA = (tid & 1) * 16;   // A: 128 m x 32 k
    const short* Asrc = Wqk + (size_t)mA * C_;
    const int kp = tid >> 4, nq = tid & 15;          // B: 2k x 4n per thread
    const float* xb = x + (size_t)b * C_ * N_;

    shortx8 a0 = *(const shortx8*)(Asrc + koA);
    shortx8 a1 = *(const shortx8*)(Asrc + koA + 8);
    float4 r0, r1;
    {
        const float* Bs = xb + (size_t)(kp * 2) * N_ + n0 + nq * 4;
        r0 = *(const float4*)(Bs);
        r1 = *(const float4*)(Bs + N_);
    }

    auto stage = [&](int buf, shortx8 s0, shortx8 s1, float4 q0, float4 q1) {
        *(shortx8*)&A_l[buf][mA][koA]     = s0;
        *(shortx8*)&A_l[buf][mA][koA + 8] = s1;
        const float* f0 = (const float*)&q0;
        const float* f1 = (const float*)&q1;
#pragma unroll
        for (int i = 0; i < 4; i++) {
            shortx2 t = { f2bf(f0[i]), f2bf(f1[i]) };
            *(shortx2*)&B_l[buf][nq * 4 + i][kp * 2] = t;
        }
    };
    stage(0, a0, a1, r0, r1);
    __syncthreads();

    const floatx4 z4 = {0.f, 0.f, 0.f, 0.f};
    floatx4 acc[4][2];
#pragma unroll
    for (int mt = 0; mt < 4; mt++) { acc[mt][0] = z4; acc[mt][1] = z4; }

    int cur = 0;
    for (int it = 0; it < 16; ++it) {
        shortx8 na0, na1; float4 nr0, nr1;
        if (it < 15) {
            const int k0 = (it + 1) * 32;
            na0 = *(const shortx8*)(Asrc + k0 + koA);
            na1 = *(const shortx8*)(Asrc + k0 + koA + 8);
            const float* Bs = xb + (size_t)(k0 + kp * 2) * N_ + n0 + nq * 4;
            nr0 = *(const float4*)(Bs);
            nr1 = *(const float4*)(Bs + N_);
        }
        shortx8 af[4];
#pragma unroll
        for (int mt = 0; mt < 4; mt++)
            af[mt] = ldf8(&A_l[cur][waveM * 64 + mt * 16 + ln][quad * 8]);
#pragma unroll
        for (int nt = 0; nt < 2; nt++) {
            shortx8 bf8 = ldf8(&B_l[cur][waveN * 32 + nt * 16 + ln][quad * 8]);
#pragma unroll
            for (int mt = 0; mt < 4; mt++)
                acc[mt][nt] = __builtin_amdgcn_mfma_f32_16x16x32_bf16(af[mt], bf8, acc[mt][nt], 0, 0, 0);
        }
        if (it < 15) stage(cur ^ 1, na0, na1, nr0, nr1);
        __syncthreads();
        cur ^= 1;
    }

    // bias
#pragma unroll
    for (int mt = 0; mt < 4; mt++)
#pragma unroll
        for (int r = 0; r < 4; r++) {
            float bias = bias_l[waveM * 64 + mt * 16 + quad * 4 + r];
#pragma unroll
            for (int nt = 0; nt < 2; nt++) acc[mt][nt][r] += bias;
        }
    // column L2 normalize (wave's 64 rows are exactly Q or exactly K)
#pragma unroll
    for (int nt = 0; nt < 2; nt++) {
        float s = 0.f;
#pragma unroll
        for (int mt = 0; mt < 4; mt++)
#pragma unroll
            for (int r = 0; r < 4; r++) s += acc[mt][nt][r] * acc[mt][nt][r];
        s += __shfl_xor(s, 16);
        s += __shfl_xor(s, 32);
        float inv = rsqrtf(s);
#pragma unroll
        for (int mt = 0; mt < 4; mt++)
#pragma unroll
            for (int r = 0; r < 4; r++) acc[mt][nt][r] *= inv;
    }

    if (waveM == 0) {            // Qn^T [n][m]
        short* Qb = Qnt + (size_t)b * N_ * CQ;
#pragma unroll
        for (int nt = 0; nt < 2; nt++) {
            int n = n0 + waveN * 32 + nt * 16 + ln;
#pragma unroll
            for (int mt = 0; mt < 4; mt++) {
                shortx4 v;
#pragma unroll
                for (int r = 0; r < 4; r++) v[r] = f2bf(acc[mt][nt][r]);
                *(shortx4*)(Qb + (size_t)n * CQ + mt * 16 + quad * 4) = v;
            }
        }
    } else {                     // Kn [m][n] + Ksum
        short* Kb = Kn + (size_t)b * CQ * N_;
#pragma unroll
        for (int mt = 0; mt < 4; mt++)
#pragma unroll
            for (int r = 0; r < 4; r++) {
                int m = mt * 16 + quad * 4 + r;
                float s = 0.f;
#pragma unroll
                for (int nt = 0; nt < 2; nt++) {
                    int n = n0 + waveN * 32 + nt * 16 + ln;
                    float v = acc[mt][nt][r];
                    Kb[(size_t)m * N_ + n] = f2bf(v);
                    s += v;
                }
                s += __shfl_xor(s, 1); s += __shfl_xor(s, 2);
                s += __shfl_xor(s, 4); s += __shfl_xor(s, 8);
                if (ln == 0) atomicAdd(&Ksum[b * CQ + m], s);
            }
    }
}

// ---------------------------------------------------------------------------
// K2: KX[m][j] += sum_n Kn[m][n]*x[j][n]; xsum[j] += sum_n x[j][n].
// grid (jt=8, ks=8, b=8) = 512 blocks; block [64m][64j] over n=512.
// ---------------------------------------------------------------------------
__global__ __launch_bounds__(256, 2) void k2_kx(
    const float* __restrict__ x, const short* __restrict__ Kn,
    float* __restrict__ KX, float* __restrict__ xsum)
{
    const int jt = blockIdx.x, ks = blockIdx.y, b = blockIdx.z;
    const int j0 = jt * 64, nbase = ks * 512;
    const int tid = threadIdx.x;
    const int lane = tid & 63, wid = tid >> 6;
    const int quad = lane >> 4, ln = lane & 15;

    __shared__ short A_l[2][64][LS];    // Kn rows m
    __shared__ short B_l[2][64][LS];    // x rows j (bf16)

    const int rA = tid >> 2, oA = (tid & 3) * 8;
    const short* Kb = Kn + (size_t)b * CQ * N_;
    const float* xb = x + (size_t)b * C_ * N_;
    const short* As = Kb + (size_t)rA * N_ + nbase + oA;
    const float* Bs = xb + (size_t)(j0 + rA) * N_ + nbase + oA;

    float xsacc = 0.f;

    shortx8 aC = *(const shortx8*)As;
    float4 b0 = *(const float4*)(Bs);
    float4 b1 = *(const float4*)(Bs + 4);

    auto stage = [&](int buf, shortx8 a, float4 q0, float4 q1) {
        *(shortx8*)&A_l[buf][rA][oA] = a;
        const float* f0 = (const float*)&q0;
        const float* f1 = (const float*)&q1;
        shortx8 t;
#pragma unroll
        for (int i = 0; i < 4; i++) {
            t[i]     = f2bf(f0[i]); xsacc += f0[i];
            t[i + 4] = f2bf(f1[i]); xsacc += f1[i];
        }
        *(shortx8*)&B_l[buf][rA][oA] = t;
    };
    stage(0, aC, b0, b1);
    __syncthreads();

    const floatx4 z4 = {0.f, 0.f, 0.f, 0.f};
    floatx4 acc[4] = {z4, z4, z4, z4};

    int cur = 0;
    for (int it = 0; it < 16; ++it) {
        shortx8 aN; float4 n0v, n1v;
        if (it < 15) {
            const int off = (it + 1) * 32;
            aN  = *(const shortx8*)(As + off);
            n0v = *(const float4*)(Bs + off);
            n1v = *(const float4*)(Bs + off + 4);
        }
        shortx8 af[4];
#pragma unroll
        for (int mt = 0; mt < 4; mt++)
            af[mt] = ldf8(&A_l[cur][mt * 16 + ln][quad * 8]);
        shortx8 bf8 = ldf8(&B_l[cur][wid * 16 + ln][quad * 8]);
#pragma unroll
        for (int mt = 0; mt < 4; mt++)
            acc[mt] = __builtin_amdgcn_mfma_f32_16x16x32_bf16(af[mt], bf8, acc[mt], 0, 0, 0);
        if (it < 15) stage(cur ^ 1, aN, n0v, n1v);
        __syncthreads();
        cur ^= 1;
    }

    xsacc += __shfl_xor(xsacc, 1);
    xsacc += __shfl_xor(xsacc, 2);
    if ((tid & 3) == 0) atomicAdd(&xsum[b * C_ + j0 + rA], xsacc);

    float* KXb = KX + (size_t)b * CQ * C_;
#pragma unroll
    for (int mt = 0; mt < 4; mt++)
#pragma unroll
        for (int r = 0; r < 4; r++) {
            int m = mt * 16 + quad * 4 + r;
            atomicAdd(&KXb[(size_t)m * C_ + j0 + wid * 16 + ln], acc[mt][r]);
        }
}

// ---------------------------------------------------------------------------
// K3: Mt[c][m] = sum_j Wv[c][j]*KX[m][j] + Ksum[m]*bv[c]  (bf16 out, full j)
//     vs[c] = sum_j Wv[c][j]*xsum[j] + N*bv[c]
// grid (ct=8, b=8) = 64 blocks.
// ---------------------------------------------------------------------------
__global__ __launch_bounds__(256, 2) void k3_m(
    const float* __restrict__ KX, const short* __restrict__ Wvb,
    const float* __restrict__ bv, const float* __restrict__ Ksum,
    const float* __restrict__ xsum,
    short* __restrict__ Mt, float* __restrict__ vs)
{
    const int ct = blockIdx.x, b = blockIdx.y;
    const int c0 = ct * 64;
    const int tid = threadIdx.x;
    const int lane = tid & 63, wid = tid >> 6;
    const int quad = lane >> 4, ln = lane & 15;

    __shared__ short A_l[2][64][LS];   // Wv rows c
    __shared__ short B_l[2][64][LS];   // KX rows m (bf16)
    __shared__ float xsl[C_], Ksl[64], bvl[64], vsp[4][64];

    xsl[tid] = xsum[(size_t)b * C_ + tid];
    xsl[tid + 256] = xsum[(size_t)b * C_ + tid + 256];
    if (tid < 64) { Ksl[tid] = Ksum[b * CQ + tid]; bvl[tid] = bv[c0 + tid]; }

    const int rA = tid >> 2, oA = (tid & 3) * 8;
    const short* As = Wvb + (size_t)(c0 + rA) * C_ + oA;
    const float* Bs = KX + ((size_t)b * CQ + rA) * C_ + oA;

    shortx8 aC = *(const shortx8*)As;
    float4 b0 = *(const float4*)(Bs);
    float4 b1 = *(const float4*)(Bs + 4);

    auto stage = [&](int buf, shortx8 a, float4 q0, float4 q1) {
        *(shortx8*)&A_l[buf][rA][oA] = a;
        const float* f0 = (const float*)&q0;
        const float* f1 = (const float*)&q1;
        shortx8 t;
#pragma unroll
        for (int i = 0; i < 4; i++) { t[i] = f2bf(f0[i]); t[i + 4] = f2bf(f1[i]); }
        *(shortx8*)&B_l[buf][rA][oA] = t;
    };
    stage(0, aC, b0, b1);
    __syncthreads();

    const floatx4 z4 = {0.f, 0.f, 0.f, 0.f};
    floatx4 acc[4] = {z4, z4, z4, z4};
    float vsacc = 0.f;
    const int cv = tid & 63;

    int cur = 0;
    for (int it = 0; it < 16; ++it) {
        shortx8 aN; float4 n0v, n1v;
        if (it < 15) {
            const int off = (it + 1) * 32;
            aN  = *(const shortx8*)(As + off);
            n0v = *(const float4*)(Bs + off);
            n1v = *(const float4*)(Bs + off + 4);
        }
        shortx8 af[4];
#pragma unroll
        for (int ct2 = 0; ct2 < 4; ct2++)
            af[ct2] = ldf8(&A_l[cur][ct2 * 16 + ln][quad * 8]);
        shortx8 bf8 = ldf8(&B_l[cur][wid * 16 + ln][quad * 8]);
#pragma unroll
        for (int ct2 = 0; ct2 < 4; ct2++)
            acc[ct2] = __builtin_amdgcn_mfma_f32_16x16x32_bf16(af[ct2], bf8, acc[ct2], 0, 0, 0);
        // vs partial from staged Wv tile
#pragma unroll
        for (int jj = 0; jj < 8; jj++)
            vsacc += bf2f(A_l[cur][cv][wid * 8 + jj]) * xsl[it * 32 + wid * 8 + jj];
        if (it < 15) stage(cur ^ 1, aN, n0v, n1v);
        __syncthreads();
        cur ^= 1;
    }

    vsp[wid][cv] = vsacc;
    __syncthreads();
    if (tid < 64)
        vs[(size_t)b * C_ + c0 + tid] =
            vsp[0][tid] + vsp[1][tid] + vsp[2][tid] + vsp[3][tid] + (float)N_ * bvl[tid];

    const int m = wid * 16 + ln;
    const float ksm = Ksl[m];
    short* Mb = Mt + (size_t)b * C_ * CQ;
#pragma unroll
    for (int ct2 = 0; ct2 < 4; ct2++)
#pragma unroll
        for (int r = 0; r < 4; r++) {
            int c = ct2 * 16 + quad * 4 + r;
            Mb[(size_t)(c0 + c) * CQ + m] = f2bf(acc[ct2][r] + ksm * bvl[c]);
        }
}

// ---------------------------------------------------------------------------
// K4: ts[n] = 1/(N + Qn[:,n].(Ksum+eps));
//     out[c][n] = gamma*ts[n]*(vs[c] + sum_m Qn[m][n]*Mt[c][m])
// grid (nt=32, ct=4, b=8), block 256 (2x2 waves, 128c x 128n, k=64).
// ---------------------------------------------------------------------------
__global__ __launch_bounds__(256, 2) void k4_out(
    const short* __restrict__ Qnt, const short* __restrict__ Mt,
    const float* __restrict__ vs, const float* __restrict__ Ksum,
    const float* __restrict__ gamma, float* __restrict__ out)
{
    const int nt = blockIdx.x, ct = blockIdx.y, b = blockIdx.z;
    const int n0 = nt * 128, c0 = ct * 128;
    const int tid = threadIdx.x;
    const int lane = tid & 63, wid = tid >> 6;
    const int waveC = wid >> 1, waveN = wid & 1;
    const int quad = lane >> 4, ln = lane & 15;

    __shared__ short A_l[128][LS2];   // Mt rows c (bf16), k=m
    __shared__ short B_l[128][LS2];   // Qnt rows n (bf16)
    __shared__ float tsl[128], vsl[128], Ks_l[64];

    {
        int c = tid >> 1, h = tid & 1;
        const short* src = Mt + ((size_t)b * C_ + c0 + c) * CQ + h * 32;
#pragma unroll
        for (int q = 0; q < 4; q++)
            *(shortx8*)&A_l[c][h * 32 + q * 8] = *(const shortx8*)(src + q * 8);
    }
    {
        int n = tid >> 1, h = tid & 1;
        const short* src = Qnt + ((size_t)b * N_ + n0 + n) * CQ + h * 32;
#pragma unroll
        for (int q = 0; q < 4; q++)
            *(shortx8*)&B_l[n][h * 32 + q * 8] = *(const shortx8*)(src + q * 8);
    }
    if (tid < 64)  Ks_l[tid] = Ksum[b * CQ + tid];
    if (tid < 128) vsl[tid]  = vs[(size_t)b * C_ + c0 + tid];
    __syncthreads();

    if (tid < 128) {
        const short* row = B_l[tid];
        float s = 0.f;
#pragma unroll
        for (int m = 0; m < 64; m++) s += bf2f(row[m]) * (Ks_l[m] + EPSF);
        tsl[tid] = 1.f / ((float)N_ + s);
    }
    __syncthreads();

    const floatx4 z4 = {0.f, 0.f, 0.f, 0.f};
    floatx4 acc[4][4];
#pragma unroll
    for (int i = 0; i < 4; i++)
#pragma unroll
        for (int j = 0; j < 4; j++) acc[i][j] = z4;

#pragma unroll
    for (int kc = 0; kc < 2; kc++) {
        shortx8 af[4];
#pragma unroll
        for (int ct2 = 0; ct2 < 4; ct2++)
            af[ct2] = ldf8(&A_l[waveC * 64 + ct2 * 16 + ln][kc * 32 + quad * 8]);
#pragma unroll
        for (int nt2 = 0; nt2 < 4; nt2++) {
            shortx8 bf8 = ldf8(&B_l[waveN * 64 + nt2 * 16 + ln][kc * 32 + quad * 8]);
#pragma unroll
            for (int ct2 = 0; ct2 < 4; ct2++)
                acc[ct2][nt2] = __builtin_amdgcn_mfma_f32_16x16x32_bf16(af[ct2], bf8, acc[ct2][nt2], 0, 0, 0);
        }
    }

    const float g = gamma[0];
    float* ob = out + (size_t)b * C_ * N_;
#pragma unroll
    for (int ct2 = 0; ct2 < 4; ct2++)
#pragma unroll
        for (int r = 0; r < 4; r++) {
            int cl = waveC * 64 + ct2 * 16 + quad * 4 + r;
            float vc = vsl[cl];
#pragma unroll
            for (int nt2 = 0; nt2 < 4; nt2++) {
                int nl = waveN * 64 + nt2 * 16 + ln;
                ob[(size_t)(c0 + cl) * N_ + n0 + nl] = g * tsl[nl] * (vc + acc[ct2][nt2][r]);
            }
        }
}

// ---------------------------------------------------------------------------
extern "C" void kernel_launch(void* const* d_in, const int* in_sizes, int n_in,
                              void* d_out, int out_size, void* d_ws, size_t ws_size,
                              hipStream_t stream)
{
    (void)in_sizes; (void)n_in; (void)out_size; (void)ws_size;
    const float* x     = (const float*)d_in[0];
    const float* Wq    = (const float*)d_in[1];
    const float* bq    = (const float*)d_in[2];
    const float* Wk    = (const float*)d_in[3];
    const float* bk    = (const float*)d_in[4];
    const float* Wv    = (const float*)d_in[5];
    const float* bv    = (const float*)d_in[6];
    const float* gamma = (const float*)d_in[7];
    float* out = (float*)d_out;

    short* Qnt = (short*)d_ws;                          // [8][4096][64] bf16
    short* Kn  = Qnt + (size_t)B_ * N_ * CQ;            // [8][64][4096] bf16
    float* Ksum = (float*)(Kn + (size_t)B_ * CQ * N_);  // [8][64]
    float* xsum = Ksum + B_ * CQ;                       // [8][512]
    float* KX   = xsum + B_ * C_;                       // [8][64][512]
    short* Mt   = (short*)(KX + (size_t)B_ * CQ * C_);  // [8][512][64] bf16
    float* vs   = (float*)(Mt + (size_t)B_ * C_ * CQ);  // [8][512]
    short* Wqk  = (short*)(vs + B_ * C_);               // [128][512] bf16
    short* Wvb  = Wqk + 2 * CQ * C_;                    // [512][512] bf16

    size_t zbytes = (size_t)(B_ * CQ + B_ * C_ + B_ * CQ * C_) * 4;
    hipMemsetAsync(Ksum, 0, zbytes, stream);

    pcast <<<dim3(320),      256, 0, stream>>>(Wq, Wk, Wv, Wqk, Wvb);
    k1_qk <<<dim3(64, 8),    256, 0, stream>>>(x, Wqk, bq, bk, Qnt, Kn, Ksum);
    k2_kx <<<dim3(8, 8, 8),  256, 0, stream>>>(x, Kn, KX, xsum);
    k3_m  <<<dim3(8, 8),     256, 0, stream>>>(KX, Wvb, bv, Ksum, xsum, Mt, vs);
    k4_out<<<dim3(32, 4, 8), 256, 0, stream>>>(Qnt, Mt, vs, Ksum, gamma, out);
}